// Round 10
// baseline (1789.389 us; speedup 1.0000x reference)
//
#include <hip/hip_runtime.h>
#include <hip/hip_bf16.h>

#define NNODE   2000
#define NG      8
#define EPG     64000
#define TSTEPS  24
#define HOR     10
#define NSTEP   (HOR-1)
#define PITCH   2048          // per-graph node pitch; row 2047 is the zero row
#define ECAP    98304         // padded CSR capacity (ushorts)
#define TILES   125           // 2000 / 16

// ---- workspace layout (bytes) ----
#define OFF_DESC    0
#define OFF_HA      196608
#define OFF_HB      2293760
#define OFF_YIN     4390912
#define OFF_YB      4456448
#define OFF_KA      4521984
#define OFF_KB      4587520
#define OFF_KC      4653056
#define OFF_S4      4718592
#define OFF_DEG     4784128
#define OFF_CUR     4792320
#define OFF_ROWP    4800512
#define OFF_DINV    4808960
#define OFF_MODES   4817152
#define OFF_WF      4817408
#define OFF_WFRAG   4868352
#define OFF_BAR     4917504   // unsigned * NG*256 per-graph barrier lines
// total ~4.93 MB

#define W0OFF 0
#define B0OFF 64
#define W1OFF 128
#define B1OFF 4224
#define W2OFF 4288
#define B2OFF 8384
#define W3OFF 8448
#define B3OFF 12544
#define W4OFF 12608
#define B4OFF 12672
#define WFTOT 12673

typedef __attribute__((ext_vector_type(8))) short short8;
typedef __attribute__((ext_vector_type(4))) float f32x4;

struct WPtrs { const void* p[10]; };

__device__ inline float tanh_fast(float x) {
    float xc = fminf(fmaxf(x, -15.f), 15.f);
    float e  = __expf(2.f * xc);
    return 1.f - 2.f / (e + 1.f);
}
__device__ inline unsigned short f2bf(float f) {
    unsigned u = __float_as_uint(f);
    u += 0x7fff + ((u >> 16) & 1);
    return (unsigned short)(u >> 16);
}
__device__ inline float bf2f(unsigned short h) {
    return __uint_as_float(((unsigned)h) << 16);
}
__device__ inline int ld_idx(const void* p, long i, int imode) {
    return imode ? (int)((const long long*)p)[i] : ((const int*)p)[i];
}

// ================= setup kernels =================

__global__ void k_detect(const void* x, const void* eidx, int* modes) {
    int lane = threadIdx.x;
    const unsigned* xw = (const unsigned*)x;
    unsigned w = xw[lane];
    int ex = (w >> 7) & 0xFF;
    unsigned long long m = __ballot(ex >= 100 && ex <= 145);
    const unsigned* ew = (const unsigned*)eidx;
    unsigned long long m2 = __ballot(ew[2*lane + 1] != 0);
    if (lane == 0) {
        modes[0] = (__popcll(m) >= 48) ? 1 : 0;
        modes[1] = (__popcll(m2) == 0) ? 1 : 0;
    }
}

// merged: deg init + desc sentinel fill + h pad-row zeroing + barrier zeroing
__global__ void k_setup0(int* deg, unsigned* desc32, unsigned* hA32, unsigned* hB32,
                         unsigned* bar) {
    int n = blockIdx.x * 256 + threadIdx.x;
    if (n < PITCH) deg[n] = (n < NNODE) ? 1 : 0;
    if (n < ECAP / 2) desc32[n] = 0x07FF07FFu;     // sentinel -> zero row 2047
    if (n < NG * 256) bar[n] = 0;
    if (n < 2 * NG * 48 * 32) {
        int b = n / (NG * 48 * 32), r = n % (NG * 48 * 32);
        int g = r / (48 * 32), rr = r % (48 * 32);
        int row = NNODE + rr / 32, fp = rr % 32;
        unsigned* pp = b ? hB32 : hA32;
        pp[(g * PITCH + row) * 32 + fp] = 0;
    }
}

__global__ void k_count(const void* eidx, const int* __restrict__ modes, int* deg) {
    int e = blockIdx.x * 256 + threadIdx.x;
    int imode = modes[1];
    int dst = ld_idx(eidx, (long)EPG + e, imode);
    atomicAdd(&deg[dst], 1);
}

__global__ __launch_bounds__(256) void k_scan(const int* __restrict__ deg, int* rowp,
                                              int* cursor, float* dinv) {
    __shared__ int part[256];
    int t = threadIdx.x, base = t * 8;
    int loc[8]; int s = 0;
    #pragma unroll
    for (int k = 0; k < 8; ++k) {
        int d = deg[base + k];
        int p = (d + 15) & ~15;
        loc[k] = p; s += p;
    }
    part[t] = s; __syncthreads();
    for (int off = 1; off < 256; off <<= 1) {
        int v = (t >= off) ? part[t - off] : 0;
        __syncthreads();
        part[t] += v;
        __syncthreads();
    }
    int run = part[t] - s;
    #pragma unroll
    for (int k = 0; k < 8; ++k) {
        rowp[base + k] = run; cursor[base + k] = run;
        int d = deg[base + k];
        dinv[base + k] = (d > 0) ? rsqrtf((float)d) : 0.f;
        run += loc[k];
    }
    if (t == 255) rowp[PITCH] = part[255];
}

__global__ void k_scatter(const void* eidx, const int* __restrict__ modes,
                          int* cursor, unsigned short* desc) {
    int idx = blockIdx.x * 256 + threadIdx.x;
    if (idx >= EPG + NNODE) return;
    int imode = modes[1];
    int s, d;
    if (idx < EPG) { s = ld_idx(eidx, idx, imode); d = ld_idx(eidx, (long)EPG + idx, imode); }
    else           { s = idx - EPG; d = s; }
    int pos = atomicAdd(&cursor[d], 1);
    desc[pos] = (unsigned short)s;
}

__global__ void k_convert(WPtrs wp, float* wf, const int* __restrict__ modes) {
    int idx = blockIdx.x * 256 + threadIdx.x;
    if (idx >= WFTOT) return;
    int fmode = modes[0];
    const int offs[10]  = {W0OFF,B0OFF,W1OFF,B1OFF,W2OFF,B2OFF,W3OFF,B3OFF,W4OFF,B4OFF};
    const int sizes[10] = {64,64,4096,64,4096,64,4096,64,64,1};
    #pragma unroll
    for (int s = 0; s < 10; ++s) {
        if (idx >= offs[s] && idx < offs[s] + sizes[s]) {
            int j = idx - offs[s];
            wf[idx] = fmode ? __bfloat162float(((const __hip_bfloat16*)wp.p[s])[j])
                            : ((const float*)wp.p[s])[j];
        }
    }
}

__global__ void k_mkfrag(const float* __restrict__ wf, short8* frag) {
    int t = blockIdx.x * 256 + threadIdx.x;
    if (t >= 3072) return;
    int lane = t & 63, half = (t >> 6) & 1, kh = (t >> 7) & 1, nb = (t >> 8) & 3, mat = t >> 10;
    const int woffs[3] = {W1OFF, W2OFF, W3OFF};
    const float* W = wf + woffs[mat];
    int n  = nb * 16 + (lane & 15);
    int k0 = kh * 32 + (lane >> 4) * 8;
    short8 v;
    #pragma unroll
    for (int j = 0; j < 8; ++j) {
        float w = W[(k0 + j) * 64 + n];
        unsigned short h = f2bf(w);
        v[j] = half ? (short)f2bf(w - bf2f(h)) : (short)h;
    }
    frag[t] = v;
}

__global__ void k_finalize(const float* __restrict__ dinv, const void* x,
                           const int* __restrict__ modes,
                           float* yin, float* yb, float* s4, void* out) {
    int idx = blockIdx.x * 256 + threadIdx.x;
    if (idx >= NG * PITCH) return;
    int g = idx >> 11, local = idx & (PITCH - 1);
    if (local >= NNODE) { yin[idx] = 0.f; yb[idx] = 0.f; s4[idx] = 0.f; return; }
    int cn = g * NNODE + local;
    float y0 = modes[0] ? __bfloat162float(((const __hip_bfloat16*)x)[cn * TSTEPS + (TSTEPS - 1)])
                        : ((const float*)x)[cn * TSTEPS + (TSTEPS - 1)];
    yin[idx] = dinv[local] * y0;
    yb[idx]  = y0;
    if (modes[0]) ((__hip_bfloat16*)out)[cn * HOR] = __float2bfloat16(y0);
    else          ((float*)out)[cn * HOR] = y0;
}

// ---- layer 0: scalar gather of yin' -> h0' (bf16); initial only ----
__global__ __launch_bounds__(256) void k_layer0(
        const float* __restrict__ yin, unsigned short* __restrict__ hout,
        const unsigned short* __restrict__ desc, const int* __restrict__ rowp,
        const float* __restrict__ dinv, const float* __restrict__ wf) {
    int lane = threadIdx.x & 63, wv = threadIdx.x >> 6;
    int b = blockIdx.x;
    int g = b & 7, local = (b >> 3) * 4 + wv;
    const float* yg = yin + g * PITCH;
    int s = rowp[local], e = rowp[local + 1];
    float acc = 0.f;
    for (int i = s + lane; i < e; i += 64) acc += yg[desc[i]];
    #pragma unroll
    for (int off = 32; off; off >>= 1) acc += __shfl_xor(acc, off);
    float dv = dinv[local];
    float o = dv * tanh_fast(dv * acc * wf[W0OFF + lane] + wf[B0OFF + lane]);
    hout[((g * PITCH + local) << 6) + lane] = f2bf(o);
}

// ---- shared heavy-tile pieces (R10: dwordx2 gather, 4 acc chains) ----
// lane = (fp2 = lane&15 feature-quad, p4 = lane>>4 edge-parity). One uint2 load
// covers feats 4fp2..4fp2+3 of one edge; 4 edges in flight per step.
__device__ __forceinline__ void gather_tile(
        const uint2* __restrict__ hg64, const unsigned short* __restrict__ desc,
        const int* __restrict__ rowp, const float* __restrict__ dinv,
        int tb, int lane, int wv, float* tile, float* dinvt) {
    int fp2 = lane & 15, p4 = lane >> 4;
    unsigned psh = (unsigned)((p4 & 1) << 4);
    bool hi = (p4 >> 1) != 0;
    #pragma unroll
    for (int r = 0; r < 4; ++r) {
        int m = (wv << 2) + r;
        int local = tb + m;
        int s = rowp[local], e = rowp[local + 1];   // multiples of 16
        float a0 = 0.f, a1 = 0.f, a2 = 0.f, a3 = 0.f;
        for (int i = s; i < e; i += 16) {
            uint4 q0 = *(const uint4*)(desc + i);       // edges i..i+7
            uint4 q1 = *(const uint4*)(desc + i + 8);   // edges i+8..i+15
            unsigned w0 = hi ? q0.y : q0.x;
            unsigned w1 = hi ? q0.w : q0.z;
            unsigned w2 = hi ? q1.y : q1.x;
            unsigned w3 = hi ? q1.w : q1.z;
            unsigned s0 = (w0 >> psh) & 0xffffu;
            unsigned s1 = (w1 >> psh) & 0xffffu;
            unsigned s2 = (w2 >> psh) & 0xffffu;
            unsigned s3 = (w3 >> psh) & 0xffffu;
            uint2 v0 = hg64[(s0 << 4) + fp2];
            uint2 v1 = hg64[(s1 << 4) + fp2];
            uint2 v2 = hg64[(s2 << 4) + fp2];
            uint2 v3 = hg64[(s3 << 4) + fp2];
            a0 += __uint_as_float(v0.x << 16); a1 += __uint_as_float(v0.x & 0xffff0000u);
            a2 += __uint_as_float(v0.y << 16); a3 += __uint_as_float(v0.y & 0xffff0000u);
            a0 += __uint_as_float(v1.x << 16); a1 += __uint_as_float(v1.x & 0xffff0000u);
            a2 += __uint_as_float(v1.y << 16); a3 += __uint_as_float(v1.y & 0xffff0000u);
            a0 += __uint_as_float(v2.x << 16); a1 += __uint_as_float(v2.x & 0xffff0000u);
            a2 += __uint_as_float(v2.y << 16); a3 += __uint_as_float(v2.y & 0xffff0000u);
            a0 += __uint_as_float(v3.x << 16); a1 += __uint_as_float(v3.x & 0xffff0000u);
            a2 += __uint_as_float(v3.y << 16); a3 += __uint_as_float(v3.y & 0xffff0000u);
        }
        float dv = dinv[local];
        a0 *= dv; a1 *= dv; a2 *= dv; a3 *= dv;
        a0 += __shfl_xor(a0, 16); a0 += __shfl_xor(a0, 32);
        a1 += __shfl_xor(a1, 16); a1 += __shfl_xor(a1, 32);
        a2 += __shfl_xor(a2, 16); a2 += __shfl_xor(a2, 32);
        a3 += __shfl_xor(a3, 16); a3 += __shfl_xor(a3, 32);
        if (p4 == 0) {
            float4* dst = (float4*)&tile[m * 68 + (fp2 << 2)];
            *dst = make_float4(a0, a1, a2, a3);
        }
        if (lane == 0) dinvt[m] = dv;
    }
}

__device__ __forceinline__ f32x4 transform_tile(
        const float* tile, const short8* __restrict__ fb,
        const float* __restrict__ wf, int boff, int lane, int wv) {
    short8 Bh0 = fb[(wv << 8) +   0 + lane];
    short8 Bl0 = fb[(wv << 8) +  64 + lane];
    short8 Bh1 = fb[(wv << 8) + 128 + lane];
    short8 Bl1 = fb[(wv << 8) + 192 + lane];
    int mrow = lane & 15, quad = lane >> 4;
    const float* arow = &tile[mrow * 68];
    float4 a0 = *(const float4*)(arow + (quad << 3));
    float4 a1 = *(const float4*)(arow + (quad << 3) + 4);
    float4 a2 = *(const float4*)(arow + 32 + (quad << 3));
    float4 a3 = *(const float4*)(arow + 32 + (quad << 3) + 4);
    float av0[8] = {a0.x, a0.y, a0.z, a0.w, a1.x, a1.y, a1.z, a1.w};
    float av1[8] = {a2.x, a2.y, a2.z, a2.w, a3.x, a3.y, a3.z, a3.w};
    short8 Ah0, Al0, Ah1, Al1;
    #pragma unroll
    for (int j = 0; j < 8; ++j) {
        unsigned short h0 = f2bf(av0[j]);
        Ah0[j] = (short)h0; Al0[j] = (short)f2bf(av0[j] - bf2f(h0));
        unsigned short h1 = f2bf(av1[j]);
        Ah1[j] = (short)h1; Al1[j] = (short)f2bf(av1[j] - bf2f(h1));
    }
    float bias = wf[boff + (wv << 4) + mrow];
    f32x4 c = {bias, bias, bias, bias};
    c = __builtin_amdgcn_mfma_f32_16x16x32_bf16(Ah0, Bh0, c, 0, 0, 0);
    c = __builtin_amdgcn_mfma_f32_16x16x32_bf16(Al0, Bh0, c, 0, 0, 0);
    c = __builtin_amdgcn_mfma_f32_16x16x32_bf16(Ah0, Bl0, c, 0, 0, 0);
    c = __builtin_amdgcn_mfma_f32_16x16x32_bf16(Ah1, Bh1, c, 0, 0, 0);
    c = __builtin_amdgcn_mfma_f32_16x16x32_bf16(Al1, Bh1, c, 0, 0, 0);
    c = __builtin_amdgcn_mfma_f32_16x16x32_bf16(Ah1, Bl1, c, 0, 0, 0);
    return c;
}

// ---- heavy middle layer (layer1 / layer2) ----
__global__ __launch_bounds__(256, 4) void k_layer(
        const unsigned short* __restrict__ hin, unsigned short* __restrict__ hout,
        const unsigned short* __restrict__ desc, const int* __restrict__ rowp,
        const float* __restrict__ dinv, const float* __restrict__ wf,
        const short8* __restrict__ frag, int mat, int boff) {
    __shared__ float tile[16 * 68];
    __shared__ float dinvt[16];
    int lane = threadIdx.x & 63, wv = threadIdx.x >> 6;
    int b = blockIdx.x;
    int g = b & 7, tb = (b >> 3) << 4;
    const uint2* hg64 = (const uint2*)(hin + ((size_t)g * PITCH << 6));

    gather_tile(hg64, desc, rowp, dinv, tb, lane, wv, tile, dinvt);
    __syncthreads();
    f32x4 c = transform_tile(tile, frag + (mat << 10), wf, boff, lane, wv);

    int mrow = lane & 15, quad = lane >> 4;
    #pragma unroll
    for (int r = 0; r < 4; ++r) {
        int m = (quad << 2) + r;
        hout[(((size_t)g * PITCH + tb + m) << 6) + (wv << 4) + mrow] = f2bf(dinvt[m] * tanh_fast(c[r]));
    }
}

// ---- fence-free per-graph epoch barrier (R8-proven; relaxed atomics only) ----
__device__ __forceinline__ void graph_barrier(unsigned* bar, int g, unsigned be,
                                              unsigned nbg, int tid) {
    __syncthreads();
    if (tid == 0) {
        unsigned* cnt = bar + (g << 8);
        unsigned* ep  = bar + (g << 8) + 64;
        if (__hip_atomic_fetch_add(cnt, 1u, __ATOMIC_RELAXED, __HIP_MEMORY_SCOPE_AGENT) + 1u == be * nbg)
            __hip_atomic_store(ep, be, __ATOMIC_RELAXED, __HIP_MEMORY_SCOPE_AGENT);
        while (__hip_atomic_load(ep, __ATOMIC_RELAXED, __HIP_MEMORY_SCOPE_AGENT) < be)
            __builtin_amdgcn_s_sleep(2);
        asm volatile("" ::: "memory");
    }
    __syncthreads();
}

// ---- fused stage tail: layer3(FUSE->s4 atomic) | barrier | prop(yin atomic) |
//      barrier | layer0 -> hA.  Cross-block arrays written in-kernel (s4,yin)
//      use LLC atomics for stores; post-barrier readers use NORMAL loads (safe:
//      neither array is normally-read pre-barrier in this kernel, and dispatch
//      start invalidated L2 -> no stale lines).  R8's mistake (atomic LOADS,
//      no L2 reuse) is avoided. ----
__global__ __launch_bounds__(256, 4) void k_stage(
        const unsigned short* __restrict__ hin, unsigned short* __restrict__ hA,
        float* s4, float* yin, float* __restrict__ yb,
        float* __restrict__ kA, float* __restrict__ kB, float* __restrict__ kC,
        const unsigned short* __restrict__ desc, const int* __restrict__ rowp,
        const float* __restrict__ dinv, const float* __restrict__ wf,
        const short8* __restrict__ frag, const int* __restrict__ modes, void* out,
        float c1, float c2, float c3, float c4, int stage, int hidx, int doC,
        unsigned be, unsigned* bar) {
    __shared__ float tile[16 * 68];
    __shared__ float dinvt[16];
    __shared__ float pd[4][16];
    int tid = threadIdx.x, lane = tid & 63, wv = tid >> 6;
    int b = blockIdx.x, g = b & 7, tb = (b >> 3) << 4;
    unsigned nbg = gridDim.x >> 3;
    int fmode = modes[0];

    // ---- phase A: layer3 + W4 fuse -> s4 (atomic stores) ----
    const uint2* hg64 = (const uint2*)(hin + ((size_t)g * PITCH << 6));
    gather_tile(hg64, desc, rowp, dinv, tb, lane, wv, tile, dinvt);
    __syncthreads();
    f32x4 c = transform_tile(tile, frag + (2 << 10), wf, B3OFF, lane, wv);
    {
        int mrow = lane & 15, quad = lane >> 4;
        float w4v = wf[W4OFF + (wv << 4) + mrow];
        #pragma unroll
        for (int r = 0; r < 4; ++r) {
            float d = tanh_fast(c[r]) * w4v;
            d += __shfl_xor(d, 1); d += __shfl_xor(d, 2);
            d += __shfl_xor(d, 4); d += __shfl_xor(d, 8);
            if (mrow == 0) pd[wv][(quad << 2) + r] = d;
        }
    }
    __syncthreads();
    if (tid < 16) {
        float v = dinvt[tid] * (pd[0][tid] + pd[1][tid] + pd[2][tid] + pd[3][tid]);
        __hip_atomic_store(&s4[g * PITCH + tb + tid], v, __ATOMIC_RELAXED, __HIP_MEMORY_SCOPE_AGENT);
    }

    graph_barrier(bar, g, be, nbg, tid);

    // ---- phase B: prop for this block's 16 nodes (s4 via normal loads) ----
    const float* sg = s4 + g * PITCH;
    float b4 = wf[B4OFF];
    #pragma unroll
    for (int r = 0; r < 4; ++r) {
        int local = tb + (wv << 2) + r;
        int s = rowp[local], e = rowp[local + 1];
        float acc = 0.f;
        for (int i = s + lane; i < e; i += 64) acc += sg[desc[i]];
        #pragma unroll
        for (int off = 32; off; off >>= 1) acc += __shfl_xor(acc, off);
        if (lane == 0) {
            int idx = g * PITCH + local;
            float dv = dinv[local];
            float k = dv * acc + b4;
            float ynew = yb[idx] + c1 * kA[idx] + c2 * kB[idx] + c3 * kC[idx] + c4 * k;
            if (stage == 0) kA[idx] = k;
            else if (stage == 1) kB[idx] = k;
            else if (stage == 2) kC[idx] = k;
            __hip_atomic_store(&yin[idx], dv * ynew, __ATOMIC_RELAXED, __HIP_MEMORY_SCOPE_AGENT);
            if (stage == 3) {
                yb[idx] = ynew;
                int cn = g * NNODE + local;
                if (fmode) ((__hip_bfloat16*)out)[cn * HOR + hidx] = __float2bfloat16(ynew);
                else       ((float*)out)[cn * HOR + hidx] = ynew;
            }
        }
    }

    if (!doC) return;                              // final stage: no next layer0
    graph_barrier(bar, g, be + 1, nbg, tid);

    // ---- phase C: layer0 for next stage (yin via normal loads -> hA) ----
    const float* yg = yin + g * PITCH;
    float w0 = wf[W0OFF + lane], b0 = wf[B0OFF + lane];
    #pragma unroll
    for (int r = 0; r < 4; ++r) {
        int local = tb + (wv << 2) + r;
        int s = rowp[local], e = rowp[local + 1];
        float acc = 0.f;
        for (int i = s + lane; i < e; i += 64) acc += yg[desc[i]];
        #pragma unroll
        for (int off = 32; off; off >>= 1) acc += __shfl_xor(acc, off);
        float dv = dinv[local];
        float o = dv * tanh_fast(dv * acc * w0 + b0);
        hA[((size_t)(g * PITCH + local) << 6) + lane] = f2bf(o);
    }
}

// ================= host =================

extern "C" void kernel_launch(void* const* d_in, const int* in_sizes, int n_in,
                              void* d_out, int out_size, void* d_ws, size_t ws_size,
                              hipStream_t stream) {
    char* ws = (char*)d_ws;
    unsigned short* desc = (unsigned short*)(ws + OFF_DESC);
    unsigned short* hA   = (unsigned short*)(ws + OFF_HA);
    unsigned short* hB   = (unsigned short*)(ws + OFF_HB);
    float* yin  = (float*)(ws + OFF_YIN);
    float* yb   = (float*)(ws + OFF_YB);
    float* kA   = (float*)(ws + OFF_KA);
    float* kB   = (float*)(ws + OFF_KB);
    float* kC   = (float*)(ws + OFF_KC);
    float* s4   = (float*)(ws + OFF_S4);
    int*   deg  = (int*)(ws + OFF_DEG);
    int*   cur  = (int*)(ws + OFF_CUR);
    int*   rowp = (int*)(ws + OFF_ROWP);
    float* dinv = (float*)(ws + OFF_DINV);
    int*   modes= (int*)(ws + OFF_MODES);
    float* wf   = (float*)(ws + OFF_WF);
    short8* wfrag = (short8*)(ws + OFF_WFRAG);
    unsigned* bar = (unsigned*)(ws + OFF_BAR);

    const void* x    = d_in[0];
    const void* eidx = d_in[1];
    WPtrs wp;
    for (int i = 0; i < 10; ++i) wp.p[i] = d_in[2 + i];

    k_detect  <<<1, 64, 0, stream>>>(x, eidx, modes);
    k_setup0  <<<192, 256, 0, stream>>>(deg, (unsigned*)desc, (unsigned*)hA, (unsigned*)hB, bar);
    k_count   <<<EPG / 256, 256, 0, stream>>>(eidx, modes, deg);
    k_scan    <<<1, 256, 0, stream>>>(deg, rowp, cur, dinv);
    k_scatter <<<(EPG + NNODE + 255) / 256, 256, 0, stream>>>(eidx, modes, cur, desc);
    k_convert <<<(WFTOT + 255) / 256, 256, 0, stream>>>(wp, wf, modes);
    k_mkfrag  <<<12, 256, 0, stream>>>(wf, wfrag);
    k_finalize<<<NG * PITCH / 256, 256, 0, stream>>>(dinv, x, modes, yin, yb, s4, d_out);

    const float dt = 10.f / 9.f, dt3 = dt / 3.f;
    const float C1[4] = {0.f,  -dt3, dt,  dt * 0.125f};
    const float C2[4] = {0.f,  0.f,  -dt, dt * 0.375f};
    const float C3[4] = {0.f,  0.f,  0.f, dt * 0.375f};
    const float C4[4] = {dt3,  dt,   dt,  dt * 0.125f};

    k_layer0<<<4000, 256, 0, stream>>>(yin, hA, desc, rowp, dinv, wf);  // initial

    unsigned be = 1;
    for (int step = 0; step < NSTEP; ++step) {
        for (int st = 0; st < 4; ++st) {
            k_layer<<<1000, 256, 0, stream>>>(hA, hB, desc, rowp, dinv, wf, wfrag, 0, B1OFF);
            k_layer<<<1000, 256, 0, stream>>>(hB, hA, desc, rowp, dinv, wf, wfrag, 1, B2OFF);
            int doC = !(step == NSTEP - 1 && st == 3);
            k_stage<<<1000, 256, 0, stream>>>(hA, hA, s4, yin, yb, kA, kB, kC,
                                              desc, rowp, dinv, wf, wfrag, modes, d_out,
                                              C1[st], C2[st], C3[st], C4[st], st, step + 1,
                                              doC, be, bar);
            be += 2;
        }
    }
}

// Round 11
// 1497.700 us; speedup vs baseline: 1.1948x; 1.1948x over previous
//
#include <hip/hip_runtime.h>
#include <hip/hip_bf16.h>

#define NNODE   2000
#define NG      8
#define EPG     64000
#define TSTEPS  24
#define HOR     10
#define NSTEP   (HOR-1)
#define PITCH   2048          // per-graph node pitch; row 2047 is the zero row
#define ECAP    98304         // padded CSR capacity (ushorts)
#define TILES   125           // 2000 / 16

// ---- workspace layout (bytes) ----
#define OFF_DESC    0
#define OFF_HA      196608
#define OFF_HB      2293760
#define OFF_YIN     4390912
#define OFF_YB      4456448
#define OFF_KA      4521984
#define OFF_KB      4587520
#define OFF_KC      4653056
#define OFF_S4      4718592
#define OFF_DEG     4784128
#define OFF_CUR     4792320
#define OFF_ROWP    4800512
#define OFF_DINV    4808960
#define OFF_MODES   4817152
#define OFF_WF      4817408
#define OFF_WFRAG   4868352
// total ~4.92 MB

#define W0OFF 0
#define B0OFF 64
#define W1OFF 128
#define B1OFF 4224
#define W2OFF 4288
#define B2OFF 8384
#define W3OFF 8448
#define B3OFF 12544
#define W4OFF 12608
#define B4OFF 12672
#define WFTOT 12673

typedef __attribute__((ext_vector_type(8))) short short8;
typedef __attribute__((ext_vector_type(4))) float f32x4;

struct WPtrs { const void* p[10]; };

__device__ inline float tanh_fast(float x) {
    float xc = fminf(fmaxf(x, -15.f), 15.f);
    float e  = __expf(2.f * xc);
    return 1.f - 2.f / (e + 1.f);
}
__device__ inline unsigned short f2bf(float f) {
    unsigned u = __float_as_uint(f);
    u += 0x7fff + ((u >> 16) & 1);
    return (unsigned short)(u >> 16);
}
__device__ inline float bf2f(unsigned short h) {
    return __uint_as_float(((unsigned)h) << 16);
}
__device__ inline float bflo(unsigned v) { return __uint_as_float(v << 16); }
__device__ inline float bfhi(unsigned v) { return __uint_as_float(v & 0xffff0000u); }
__device__ inline int ld_idx(const void* p, long i, int imode) {
    return imode ? (int)((const long long*)p)[i] : ((const int*)p)[i];
}

// ================= setup kernels =================

__global__ void k_detect(const void* x, const void* eidx, int* modes) {
    int lane = threadIdx.x;
    const unsigned* xw = (const unsigned*)x;
    unsigned w = xw[lane];
    int ex = (w >> 7) & 0xFF;
    unsigned long long m = __ballot(ex >= 100 && ex <= 145);
    const unsigned* ew = (const unsigned*)eidx;
    unsigned long long m2 = __ballot(ew[2*lane + 1] != 0);
    if (lane == 0) {
        modes[0] = (__popcll(m) >= 48) ? 1 : 0;
        modes[1] = (__popcll(m2) == 0) ? 1 : 0;
    }
}

// merged: deg init + desc sentinel fill + h pad-row zeroing
__global__ void k_setup0(int* deg, unsigned* desc32, unsigned* hA32, unsigned* hB32) {
    int n = blockIdx.x * 256 + threadIdx.x;
    if (n < PITCH) deg[n] = (n < NNODE) ? 1 : 0;
    if (n < ECAP / 2) desc32[n] = 0x07FF07FFu;     // sentinel -> zero row 2047
    if (n < 2 * NG * 48 * 32) {
        int b = n / (NG * 48 * 32), r = n % (NG * 48 * 32);
        int g = r / (48 * 32), rr = r % (48 * 32);
        int row = NNODE + rr / 32, fp = rr % 32;
        unsigned* pp = b ? hB32 : hA32;
        pp[(g * PITCH + row) * 32 + fp] = 0;
    }
}

__global__ void k_count(const void* eidx, const int* __restrict__ modes, int* deg) {
    int e = blockIdx.x * 256 + threadIdx.x;
    int imode = modes[1];
    int dst = ld_idx(eidx, (long)EPG + e, imode);
    atomicAdd(&deg[dst], 1);
}

__global__ __launch_bounds__(256) void k_scan(const int* __restrict__ deg, int* rowp,
                                              int* cursor, float* dinv) {
    __shared__ int part[256];
    int t = threadIdx.x, base = t * 8;
    int loc[8]; int s = 0;
    #pragma unroll
    for (int k = 0; k < 8; ++k) {
        int d = deg[base + k];
        int p = (d + 15) & ~15;
        loc[k] = p; s += p;
    }
    part[t] = s; __syncthreads();
    for (int off = 1; off < 256; off <<= 1) {
        int v = (t >= off) ? part[t - off] : 0;
        __syncthreads();
        part[t] += v;
        __syncthreads();
    }
    int run = part[t] - s;
    #pragma unroll
    for (int k = 0; k < 8; ++k) {
        rowp[base + k] = run; cursor[base + k] = run;
        int d = deg[base + k];
        dinv[base + k] = (d > 0) ? rsqrtf((float)d) : 0.f;
        run += loc[k];
    }
    if (t == 255) rowp[PITCH] = part[255];
}

__global__ void k_scatter(const void* eidx, const int* __restrict__ modes,
                          int* cursor, unsigned short* desc) {
    int idx = blockIdx.x * 256 + threadIdx.x;
    if (idx >= EPG + NNODE) return;
    int imode = modes[1];
    int s, d;
    if (idx < EPG) { s = ld_idx(eidx, idx, imode); d = ld_idx(eidx, (long)EPG + idx, imode); }
    else           { s = idx - EPG; d = s; }
    int pos = atomicAdd(&cursor[d], 1);
    desc[pos] = (unsigned short)s;
}

__global__ void k_convert(WPtrs wp, float* wf, const int* __restrict__ modes) {
    int idx = blockIdx.x * 256 + threadIdx.x;
    if (idx >= WFTOT) return;
    int fmode = modes[0];
    const int offs[10]  = {W0OFF,B0OFF,W1OFF,B1OFF,W2OFF,B2OFF,W3OFF,B3OFF,W4OFF,B4OFF};
    const int sizes[10] = {64,64,4096,64,4096,64,4096,64,64,1};
    #pragma unroll
    for (int s = 0; s < 10; ++s) {
        if (idx >= offs[s] && idx < offs[s] + sizes[s]) {
            int j = idx - offs[s];
            wf[idx] = fmode ? __bfloat162float(((const __hip_bfloat16*)wp.p[s])[j])
                            : ((const float*)wp.p[s])[j];
        }
    }
}

__global__ void k_mkfrag(const float* __restrict__ wf, short8* frag) {
    int t = blockIdx.x * 256 + threadIdx.x;
    if (t >= 3072) return;
    int lane = t & 63, half = (t >> 6) & 1, kh = (t >> 7) & 1, nb = (t >> 8) & 3, mat = t >> 10;
    const int woffs[3] = {W1OFF, W2OFF, W3OFF};
    const float* W = wf + woffs[mat];
    int n  = nb * 16 + (lane & 15);
    int k0 = kh * 32 + (lane >> 4) * 8;
    short8 v;
    #pragma unroll
    for (int j = 0; j < 8; ++j) {
        float w = W[(k0 + j) * 64 + n];
        unsigned short h = f2bf(w);
        v[j] = half ? (short)f2bf(w - bf2f(h)) : (short)h;
    }
    frag[t] = v;
}

__global__ void k_finalize(const float* __restrict__ dinv, const void* x,
                           const int* __restrict__ modes,
                           float* yin, float* yb, float* s4, void* out) {
    int idx = blockIdx.x * 256 + threadIdx.x;
    if (idx >= NG * PITCH) return;
    int g = idx >> 11, local = idx & (PITCH - 1);
    if (local >= NNODE) { yin[idx] = 0.f; yb[idx] = 0.f; s4[idx] = 0.f; return; }
    int cn = g * NNODE + local;
    float y0 = modes[0] ? __bfloat162float(((const __hip_bfloat16*)x)[cn * TSTEPS + (TSTEPS - 1)])
                        : ((const float*)x)[cn * TSTEPS + (TSTEPS - 1)];
    yin[idx] = dinv[local] * y0;
    yb[idx]  = y0;
    if (modes[0]) ((__hip_bfloat16*)out)[cn * HOR] = __float2bfloat16(y0);
    else          ((float*)out)[cn * HOR] = y0;
}

// ---- layer 0: scalar gather of yin' -> h0' (bf16) ----
__global__ __launch_bounds__(256) void k_layer0(
        const float* __restrict__ yin, unsigned short* __restrict__ hout,
        const unsigned short* __restrict__ desc, const int* __restrict__ rowp,
        const float* __restrict__ dinv, const float* __restrict__ wf) {
    int lane = threadIdx.x & 63, wv = threadIdx.x >> 6;
    int b = blockIdx.x;
    int g = b & 7, local = (b >> 3) * 4 + wv;
    const float* yg = yin + g * PITCH;
    int s = rowp[local], e = rowp[local + 1];
    float acc = 0.f;
    for (int i = s + lane; i < e; i += 64) acc += yg[desc[i]];
    #pragma unroll
    for (int off = 32; off; off >>= 1) acc += __shfl_xor(acc, off);
    float dv = dinv[local];
    float o = dv * tanh_fast(dv * acc * wf[W0OFF + lane] + wf[B0OFF + lane]);
    hout[((g * PITCH + local) << 6) + lane] = f2bf(o);
}

// ---- R11 gather: dwordx4 rows + broadcast scalar desc; 8 acc chains ----
// lane = (fp3 = lane&7 feature-octet, p8 = lane>>3 edge-slot). Per 16-edge
// step: 2 ushort desc loads (8-lane broadcast) + 2 uint4 row loads per lane
// (vs 8 dword loads in R9). No per-edge register selects (R10's cndmask tax).
__device__ __forceinline__ void gather_tile(
        const uint4* __restrict__ hg128, const unsigned short* __restrict__ desc,
        const int* __restrict__ rowp, const float* __restrict__ dinv,
        int tb, int lane, int wv, float* tile, float* dinvt) {
    int fp3 = lane & 7, p8 = lane >> 3;
    #pragma unroll
    for (int r = 0; r < 4; ++r) {
        int m = (wv << 2) + r;
        int local = tb + m;
        int s = rowp[local], e = rowp[local + 1];   // multiples of 16
        float a0 = 0.f, a1 = 0.f, a2 = 0.f, a3 = 0.f;
        float a4 = 0.f, a5 = 0.f, a6 = 0.f, a7 = 0.f;
        for (int i = s; i < e; i += 16) {
            unsigned e0 = desc[i + p8];
            unsigned e1 = desc[i + 8 + p8];
            uint4 v0 = hg128[(e0 << 3) + fp3];
            uint4 v1 = hg128[(e1 << 3) + fp3];
            a0 += bflo(v0.x); a1 += bfhi(v0.x);
            a2 += bflo(v0.y); a3 += bfhi(v0.y);
            a4 += bflo(v0.z); a5 += bfhi(v0.z);
            a6 += bflo(v0.w); a7 += bfhi(v0.w);
            a0 += bflo(v1.x); a1 += bfhi(v1.x);
            a2 += bflo(v1.y); a3 += bfhi(v1.y);
            a4 += bflo(v1.z); a5 += bfhi(v1.z);
            a6 += bflo(v1.w); a7 += bfhi(v1.w);
        }
        float dv = dinv[local];
        a0 *= dv; a1 *= dv; a2 *= dv; a3 *= dv;
        a4 *= dv; a5 *= dv; a6 *= dv; a7 *= dv;
        // reduce across the 8 edge-slot lanes (stride 8)
        a0 += __shfl_xor(a0, 8); a0 += __shfl_xor(a0, 16); a0 += __shfl_xor(a0, 32);
        a1 += __shfl_xor(a1, 8); a1 += __shfl_xor(a1, 16); a1 += __shfl_xor(a1, 32);
        a2 += __shfl_xor(a2, 8); a2 += __shfl_xor(a2, 16); a2 += __shfl_xor(a2, 32);
        a3 += __shfl_xor(a3, 8); a3 += __shfl_xor(a3, 16); a3 += __shfl_xor(a3, 32);
        a4 += __shfl_xor(a4, 8); a4 += __shfl_xor(a4, 16); a4 += __shfl_xor(a4, 32);
        a5 += __shfl_xor(a5, 8); a5 += __shfl_xor(a5, 16); a5 += __shfl_xor(a5, 32);
        a6 += __shfl_xor(a6, 8); a6 += __shfl_xor(a6, 16); a6 += __shfl_xor(a6, 32);
        a7 += __shfl_xor(a7, 8); a7 += __shfl_xor(a7, 16); a7 += __shfl_xor(a7, 32);
        if (p8 == 0) {
            float4* dst = (float4*)&tile[m * 68 + (fp3 << 3)];
            dst[0] = make_float4(a0, a1, a2, a3);
            dst[1] = make_float4(a4, a5, a6, a7);
        }
        if (lane == 0) dinvt[m] = dv;
    }
}

__device__ __forceinline__ f32x4 transform_tile(
        const float* tile, const short8* __restrict__ fb,
        const float* __restrict__ wf, int boff, int lane, int wv) {
    short8 Bh0 = fb[(wv << 8) +   0 + lane];
    short8 Bl0 = fb[(wv << 8) +  64 + lane];
    short8 Bh1 = fb[(wv << 8) + 128 + lane];
    short8 Bl1 = fb[(wv << 8) + 192 + lane];
    int mrow = lane & 15, quad = lane >> 4;
    const float* arow = &tile[mrow * 68];
    float4 a0 = *(const float4*)(arow + (quad << 3));
    float4 a1 = *(const float4*)(arow + (quad << 3) + 4);
    float4 a2 = *(const float4*)(arow + 32 + (quad << 3));
    float4 a3 = *(const float4*)(arow + 32 + (quad << 3) + 4);
    float av0[8] = {a0.x, a0.y, a0.z, a0.w, a1.x, a1.y, a1.z, a1.w};
    float av1[8] = {a2.x, a2.y, a2.z, a2.w, a3.x, a3.y, a3.z, a3.w};
    short8 Ah0, Al0, Ah1, Al1;
    #pragma unroll
    for (int j = 0; j < 8; ++j) {
        unsigned short h0 = f2bf(av0[j]);
        Ah0[j] = (short)h0; Al0[j] = (short)f2bf(av0[j] - bf2f(h0));
        unsigned short h1 = f2bf(av1[j]);
        Ah1[j] = (short)h1; Al1[j] = (short)f2bf(av1[j] - bf2f(h1));
    }
    float bias = wf[boff + (wv << 4) + mrow];
    f32x4 c = {bias, bias, bias, bias};
    c = __builtin_amdgcn_mfma_f32_16x16x32_bf16(Ah0, Bh0, c, 0, 0, 0);
    c = __builtin_amdgcn_mfma_f32_16x16x32_bf16(Al0, Bh0, c, 0, 0, 0);
    c = __builtin_amdgcn_mfma_f32_16x16x32_bf16(Ah0, Bl0, c, 0, 0, 0);
    c = __builtin_amdgcn_mfma_f32_16x16x32_bf16(Ah1, Bh1, c, 0, 0, 0);
    c = __builtin_amdgcn_mfma_f32_16x16x32_bf16(Al1, Bh1, c, 0, 0, 0);
    c = __builtin_amdgcn_mfma_f32_16x16x32_bf16(Ah1, Bl1, c, 0, 0, 0);
    return c;
}

// ---- heavy layers (R9 structure + R11 gather) ----
template<int FUSE>
__global__ __launch_bounds__(256, 4) void k_layer(
        const unsigned short* __restrict__ hin, unsigned short* __restrict__ hout,
        float* __restrict__ s4,
        const unsigned short* __restrict__ desc, const int* __restrict__ rowp,
        const float* __restrict__ dinv, const float* __restrict__ wf,
        const short8* __restrict__ frag, int mat, int boff) {
    __shared__ float tile[16 * 68];
    __shared__ float dinvt[16];
    __shared__ float pd[4][16];
    int lane = threadIdx.x & 63, wv = threadIdx.x >> 6;
    int b = blockIdx.x;
    int g = b & 7, tb = (b >> 3) << 4;
    const uint4* hg128 = (const uint4*)(hin + ((size_t)g * PITCH << 6));

    gather_tile(hg128, desc, rowp, dinv, tb, lane, wv, tile, dinvt);
    __syncthreads();
    f32x4 c = transform_tile(tile, frag + (mat << 10), wf, boff, lane, wv);

    int mrow = lane & 15, quad = lane >> 4;
    if (!FUSE) {
        #pragma unroll
        for (int r = 0; r < 4; ++r) {
            int m = (quad << 2) + r;
            hout[(((size_t)g * PITCH + tb + m) << 6) + (wv << 4) + mrow] = f2bf(dinvt[m] * tanh_fast(c[r]));
        }
    } else {
        float w4v = wf[W4OFF + (wv << 4) + mrow];
        #pragma unroll
        for (int r = 0; r < 4; ++r) {
            float d = tanh_fast(c[r]) * w4v;
            d += __shfl_xor(d, 1); d += __shfl_xor(d, 2);
            d += __shfl_xor(d, 4); d += __shfl_xor(d, 8);
            if (mrow == 0) pd[wv][(quad << 2) + r] = d;
        }
        __syncthreads();
        if (threadIdx.x < 16)
            s4[g * PITCH + tb + threadIdx.x] = dinvt[threadIdx.x] *
                (pd[0][threadIdx.x] + pd[1][threadIdx.x] + pd[2][threadIdx.x] + pd[3][threadIdx.x]);
    }
}

// ---- final propagation + RK4 stage combine ----
__global__ __launch_bounds__(256) void k_prop(
        const float* __restrict__ s4, const unsigned short* __restrict__ desc,
        const int* __restrict__ rowp, const float* __restrict__ dinv,
        const float* __restrict__ wf,
        float* yin, float* yb, float* kA, float* kB, float* kC,
        float c1, float c2, float c3, float c4, int stage,
        const int* __restrict__ modes, void* out, int hidx) {
    int lane = threadIdx.x & 63, wv = threadIdx.x >> 6;
    int b = blockIdx.x;
    int g = b & 7, local = (b >> 3) * 4 + wv;
    const float* sg = s4 + g * PITCH;
    int s = rowp[local], e = rowp[local + 1];
    float acc = 0.f;
    for (int i = s + lane; i < e; i += 64) acc += sg[desc[i]];
    #pragma unroll
    for (int off = 32; off; off >>= 1) acc += __shfl_xor(acc, off);
    if (lane == 0) {
        int idx = g * PITCH + local;
        float dv = dinv[local];
        float k = dv * acc + wf[B4OFF];
        float ynew = yb[idx] + c1 * kA[idx] + c2 * kB[idx] + c3 * kC[idx] + c4 * k;
        if (stage == 0) kA[idx] = k;
        else if (stage == 1) kB[idx] = k;
        else if (stage == 2) kC[idx] = k;
        yin[idx] = dv * ynew;
        if (stage == 3) {
            yb[idx] = ynew;
            int cn = g * NNODE + local;
            if (modes[0]) ((__hip_bfloat16*)out)[cn * HOR + hidx] = __float2bfloat16(ynew);
            else          ((float*)out)[cn * HOR + hidx] = ynew;
        }
    }
}

// ================= host =================

extern "C" void kernel_launch(void* const* d_in, const int* in_sizes, int n_in,
                              void* d_out, int out_size, void* d_ws, size_t ws_size,
                              hipStream_t stream) {
    char* ws = (char*)d_ws;
    unsigned short* desc = (unsigned short*)(ws + OFF_DESC);
    unsigned short* hA   = (unsigned short*)(ws + OFF_HA);
    unsigned short* hB   = (unsigned short*)(ws + OFF_HB);
    float* yin  = (float*)(ws + OFF_YIN);
    float* yb   = (float*)(ws + OFF_YB);
    float* kA   = (float*)(ws + OFF_KA);
    float* kB   = (float*)(ws + OFF_KB);
    float* kC   = (float*)(ws + OFF_KC);
    float* s4   = (float*)(ws + OFF_S4);
    int*   deg  = (int*)(ws + OFF_DEG);
    int*   cur  = (int*)(ws + OFF_CUR);
    int*   rowp = (int*)(ws + OFF_ROWP);
    float* dinv = (float*)(ws + OFF_DINV);
    int*   modes= (int*)(ws + OFF_MODES);
    float* wf   = (float*)(ws + OFF_WF);
    short8* wfrag = (short8*)(ws + OFF_WFRAG);

    const void* x    = d_in[0];
    const void* eidx = d_in[1];
    WPtrs wp;
    for (int i = 0; i < 10; ++i) wp.p[i] = d_in[2 + i];

    k_detect  <<<1, 64, 0, stream>>>(x, eidx, modes);
    k_setup0  <<<192, 256, 0, stream>>>(deg, (unsigned*)desc, (unsigned*)hA, (unsigned*)hB);
    k_count   <<<EPG / 256, 256, 0, stream>>>(eidx, modes, deg);
    k_scan    <<<1, 256, 0, stream>>>(deg, rowp, cur, dinv);
    k_scatter <<<(EPG + NNODE + 255) / 256, 256, 0, stream>>>(eidx, modes, cur, desc);
    k_convert <<<(WFTOT + 255) / 256, 256, 0, stream>>>(wp, wf, modes);
    k_mkfrag  <<<12, 256, 0, stream>>>(wf, wfrag);
    k_finalize<<<NG * PITCH / 256, 256, 0, stream>>>(dinv, x, modes, yin, yb, s4, d_out);

    const float dt = 10.f / 9.f, dt3 = dt / 3.f;
    const float C1[4] = {0.f,  -dt3, dt,  dt * 0.125f};
    const float C2[4] = {0.f,  0.f,  -dt, dt * 0.375f};
    const float C3[4] = {0.f,  0.f,  0.f, dt * 0.375f};
    const float C4[4] = {dt3,  dt,   dt,  dt * 0.125f};

    k_layer0<<<4000, 256, 0, stream>>>(yin, hA, desc, rowp, dinv, wf);  // initial

    for (int step = 0; step < NSTEP; ++step) {
        for (int st = 0; st < 4; ++st) {
            k_layer<0><<<1000, 256, 0, stream>>>(hA, hB, nullptr, desc, rowp, dinv, wf, wfrag, 0, B1OFF);
            k_layer<0><<<1000, 256, 0, stream>>>(hB, hA, nullptr, desc, rowp, dinv, wf, wfrag, 1, B2OFF);
            k_layer<1><<<1000, 256, 0, stream>>>(hA, nullptr, s4, desc, rowp, dinv, wf, wfrag, 2, B3OFF);
            k_prop    <<<4000, 256, 0, stream>>>(s4, desc, rowp, dinv, wf, yin, yb, kA, kB, kC,
                                                 C1[st], C2[st], C3[st], C4[st], st,
                                                 modes, d_out, step + 1);
            if (step < NSTEP - 1 || st < 3)
                k_layer0<<<4000, 256, 0, stream>>>(yin, hA, desc, rowp, dinv, wf);
        }
    }
}

// Round 12
// 1401.316 us; speedup vs baseline: 1.2769x; 1.0688x over previous
//
#include <hip/hip_runtime.h>
#include <hip/hip_bf16.h>

#define NNODE   2000
#define NG      8
#define EPG     64000
#define TSTEPS  24
#define HOR     10
#define NSTEP   (HOR-1)
#define PITCH   2048          // per-graph node pitch; row 2047 is the zero row
#define ECAP    98304         // padded CSR capacity (ushorts)
#define TILES   125           // 2000 / 16

// ---- workspace layout (bytes) ----
#define OFF_DESC    0
#define OFF_HA      196608
#define OFF_HB      2293760
#define OFF_YIN     4390912
#define OFF_YB      4456448
#define OFF_KA      4521984
#define OFF_KB      4587520
#define OFF_KC      4653056
#define OFF_S4      4718592
#define OFF_DEG     4784128
#define OFF_CUR     4792320
#define OFF_ROWP    4800512
#define OFF_DINV    4808960
#define OFF_MODES   4817152
#define OFF_WF      4817408
#define OFF_WFRAG   4868352
// total ~4.92 MB

#define W0OFF 0
#define B0OFF 64
#define W1OFF 128
#define B1OFF 4224
#define W2OFF 4288
#define B2OFF 8384
#define W3OFF 8448
#define B3OFF 12544
#define W4OFF 12608
#define B4OFF 12672
#define WFTOT 12673

typedef __attribute__((ext_vector_type(8))) short short8;
typedef __attribute__((ext_vector_type(4))) float f32x4;

struct WPtrs { const void* p[10]; };

__device__ inline float tanh_fast(float x) {
    float xc = fminf(fmaxf(x, -15.f), 15.f);
    float e  = __expf(2.f * xc);
    return 1.f - 2.f / (e + 1.f);
}
__device__ inline unsigned short f2bf(float f) {
    unsigned u = __float_as_uint(f);
    u += 0x7fff + ((u >> 16) & 1);
    return (unsigned short)(u >> 16);
}
__device__ inline float bf2f(unsigned short h) {
    return __uint_as_float(((unsigned)h) << 16);
}
__device__ inline float bflo(unsigned v) { return __uint_as_float(v << 16); }
__device__ inline float bfhi(unsigned v) { return __uint_as_float(v & 0xffff0000u); }
__device__ inline int ld_idx(const void* p, long i, int imode) {
    return imode ? (int)((const long long*)p)[i] : ((const int*)p)[i];
}

// ================= setup kernels =================

__global__ void k_detect(const void* x, const void* eidx, int* modes) {
    int lane = threadIdx.x;
    const unsigned* xw = (const unsigned*)x;
    unsigned w = xw[lane];
    int ex = (w >> 7) & 0xFF;
    unsigned long long m = __ballot(ex >= 100 && ex <= 145);
    const unsigned* ew = (const unsigned*)eidx;
    unsigned long long m2 = __ballot(ew[2*lane + 1] != 0);
    if (lane == 0) {
        modes[0] = (__popcll(m) >= 48) ? 1 : 0;
        modes[1] = (__popcll(m2) == 0) ? 1 : 0;
    }
}

// merged: deg init + desc sentinel fill + h pad-row zeroing
__global__ void k_setup0(int* deg, unsigned* desc32, unsigned* hA32, unsigned* hB32) {
    int n = blockIdx.x * 256 + threadIdx.x;
    if (n < PITCH) deg[n] = (n < NNODE) ? 1 : 0;
    if (n < ECAP / 2) desc32[n] = 0x07FF07FFu;     // sentinel -> zero row 2047
    if (n < 2 * NG * 48 * 32) {
        int b = n / (NG * 48 * 32), r = n % (NG * 48 * 32);
        int g = r / (48 * 32), rr = r % (48 * 32);
        int row = NNODE + rr / 32, fp = rr % 32;
        unsigned* pp = b ? hB32 : hA32;
        pp[(g * PITCH + row) * 32 + fp] = 0;
    }
}

__global__ void k_count(const void* eidx, const int* __restrict__ modes, int* deg) {
    int e = blockIdx.x * 256 + threadIdx.x;
    int imode = modes[1];
    int dst = ld_idx(eidx, (long)EPG + e, imode);
    atomicAdd(&deg[dst], 1);
}

__global__ __launch_bounds__(256) void k_scan(const int* __restrict__ deg, int* rowp,
                                              int* cursor, float* dinv) {
    __shared__ int part[256];
    int t = threadIdx.x, base = t * 8;
    int loc[8]; int s = 0;
    #pragma unroll
    for (int k = 0; k < 8; ++k) {
        int d = deg[base + k];
        int p = (d + 15) & ~15;
        loc[k] = p; s += p;
    }
    part[t] = s; __syncthreads();
    for (int off = 1; off < 256; off <<= 1) {
        int v = (t >= off) ? part[t - off] : 0;
        __syncthreads();
        part[t] += v;
        __syncthreads();
    }
    int run = part[t] - s;
    #pragma unroll
    for (int k = 0; k < 8; ++k) {
        rowp[base + k] = run; cursor[base + k] = run;
        int d = deg[base + k];
        dinv[base + k] = (d > 0) ? rsqrtf((float)d) : 0.f;
        run += loc[k];
    }
    if (t == 255) rowp[PITCH] = part[255];
}

__global__ void k_scatter(const void* eidx, const int* __restrict__ modes,
                          int* cursor, unsigned short* desc) {
    int idx = blockIdx.x * 256 + threadIdx.x;
    if (idx >= EPG + NNODE) return;
    int imode = modes[1];
    int s, d;
    if (idx < EPG) { s = ld_idx(eidx, idx, imode); d = ld_idx(eidx, (long)EPG + idx, imode); }
    else           { s = idx - EPG; d = s; }
    int pos = atomicAdd(&cursor[d], 1);
    desc[pos] = (unsigned short)s;
}

__global__ void k_convert(WPtrs wp, float* wf, const int* __restrict__ modes) {
    int idx = blockIdx.x * 256 + threadIdx.x;
    if (idx >= WFTOT) return;
    int fmode = modes[0];
    const int offs[10]  = {W0OFF,B0OFF,W1OFF,B1OFF,W2OFF,B2OFF,W3OFF,B3OFF,W4OFF,B4OFF};
    const int sizes[10] = {64,64,4096,64,4096,64,4096,64,64,1};
    #pragma unroll
    for (int s = 0; s < 10; ++s) {
        if (idx >= offs[s] && idx < offs[s] + sizes[s]) {
            int j = idx - offs[s];
            wf[idx] = fmode ? __bfloat162float(((const __hip_bfloat16*)wp.p[s])[j])
                            : ((const float*)wp.p[s])[j];
        }
    }
}

__global__ void k_mkfrag(const float* __restrict__ wf, short8* frag) {
    int t = blockIdx.x * 256 + threadIdx.x;
    if (t >= 3072) return;
    int lane = t & 63, half = (t >> 6) & 1, kh = (t >> 7) & 1, nb = (t >> 8) & 3, mat = t >> 10;
    const int woffs[3] = {W1OFF, W2OFF, W3OFF};
    const float* W = wf + woffs[mat];
    int n  = nb * 16 + (lane & 15);
    int k0 = kh * 32 + (lane >> 4) * 8;
    short8 v;
    #pragma unroll
    for (int j = 0; j < 8; ++j) {
        float w = W[(k0 + j) * 64 + n];
        unsigned short h = f2bf(w);
        v[j] = half ? (short)f2bf(w - bf2f(h)) : (short)h;
    }
    frag[t] = v;
}

__global__ void k_finalize(const float* __restrict__ dinv, const void* x,
                           const int* __restrict__ modes,
                           float* yin, float* yb, float* s4, void* out) {
    int idx = blockIdx.x * 256 + threadIdx.x;
    if (idx >= NG * PITCH) return;
    int g = idx >> 11, local = idx & (PITCH - 1);
    if (local >= NNODE) { yin[idx] = 0.f; yb[idx] = 0.f; s4[idx] = 0.f; return; }
    int cn = g * NNODE + local;
    float y0 = modes[0] ? __bfloat162float(((const __hip_bfloat16*)x)[cn * TSTEPS + (TSTEPS - 1)])
                        : ((const float*)x)[cn * TSTEPS + (TSTEPS - 1)];
    yin[idx] = dinv[local] * y0;
    yb[idx]  = y0;
    if (modes[0]) ((__hip_bfloat16*)out)[cn * HOR] = __float2bfloat16(y0);
    else          ((float*)out)[cn * HOR] = y0;
}

// ---- layer 0 (R12): 16 lanes per node, 4 nodes/wave, tile/block, grid 1000.
// Rows padded to x16 -> zero predication; Z broadcast via shfl for row write. ----
__global__ __launch_bounds__(256) void k_layer0(
        const float* __restrict__ yin, unsigned short* __restrict__ hout,
        const unsigned short* __restrict__ desc, const int* __restrict__ rowp,
        const float* __restrict__ dinv, const float* __restrict__ wf) {
    int lane = threadIdx.x & 63, wv = threadIdx.x >> 6;
    int b = blockIdx.x;
    int g = b & 7, tb = (b >> 3) << 4;
    const float* yg = yin + g * PITCH;
    int grp = lane >> 4, j = lane & 15;
    int local = tb + (wv << 2) + grp;
    int s = rowp[local], e = rowp[local + 1];
    float acc = 0.f;
    for (int i = s + j; i < e; i += 16) acc += yg[desc[i]];
    acc += __shfl_xor(acc, 1); acc += __shfl_xor(acc, 2);
    acc += __shfl_xor(acc, 4); acc += __shfl_xor(acc, 8);
    float w0 = wf[W0OFF + lane], b0 = wf[B0OFF + lane];
    #pragma unroll
    for (int r = 0; r < 4; ++r) {
        float Z = __shfl(acc, r << 4);
        int ln = tb + (wv << 2) + r;
        float dv = dinv[ln];
        float o = dv * tanh_fast(dv * Z * w0 + b0);
        hout[((size_t)(g * PITCH + ln) << 6) + lane] = f2bf(o);
    }
}

// ---- R12 heavy gather: dwordx4 rows, 32-edge unroll (4 row-loads in flight) ----
// lane = (fp3 = lane&7 feature-octet, p8 = lane>>3 edge-slot).
__device__ __forceinline__ void acc8(uint4 v, float& a0, float& a1, float& a2, float& a3,
                                     float& a4, float& a5, float& a6, float& a7) {
    a0 += bflo(v.x); a1 += bfhi(v.x);
    a2 += bflo(v.y); a3 += bfhi(v.y);
    a4 += bflo(v.z); a5 += bfhi(v.z);
    a6 += bflo(v.w); a7 += bfhi(v.w);
}

__device__ __forceinline__ void gather_tile(
        const uint4* __restrict__ hg128, const unsigned short* __restrict__ desc,
        const int* __restrict__ rowp, const float* __restrict__ dinv,
        int tb, int lane, int wv, float* tile, float* dinvt) {
    int fp3 = lane & 7, p8 = lane >> 3;
    #pragma unroll
    for (int r = 0; r < 4; ++r) {
        int m = (wv << 2) + r;
        int local = tb + m;
        int s = rowp[local], e = rowp[local + 1];   // multiples of 16
        float a0 = 0.f, a1 = 0.f, a2 = 0.f, a3 = 0.f;
        float a4 = 0.f, a5 = 0.f, a6 = 0.f, a7 = 0.f;
        int i = s;
        for (; i + 32 <= e; i += 32) {
            unsigned e0 = desc[i + p8];
            unsigned e1 = desc[i + 8 + p8];
            unsigned e2 = desc[i + 16 + p8];
            unsigned e3 = desc[i + 24 + p8];
            uint4 v0 = hg128[(e0 << 3) + fp3];
            uint4 v1 = hg128[(e1 << 3) + fp3];
            uint4 v2 = hg128[(e2 << 3) + fp3];
            uint4 v3 = hg128[(e3 << 3) + fp3];
            acc8(v0, a0, a1, a2, a3, a4, a5, a6, a7);
            acc8(v1, a0, a1, a2, a3, a4, a5, a6, a7);
            acc8(v2, a0, a1, a2, a3, a4, a5, a6, a7);
            acc8(v3, a0, a1, a2, a3, a4, a5, a6, a7);
        }
        if (i < e) {
            unsigned e0 = desc[i + p8];
            unsigned e1 = desc[i + 8 + p8];
            uint4 v0 = hg128[(e0 << 3) + fp3];
            uint4 v1 = hg128[(e1 << 3) + fp3];
            acc8(v0, a0, a1, a2, a3, a4, a5, a6, a7);
            acc8(v1, a0, a1, a2, a3, a4, a5, a6, a7);
        }
        float dv = dinv[local];
        a0 *= dv; a1 *= dv; a2 *= dv; a3 *= dv;
        a4 *= dv; a5 *= dv; a6 *= dv; a7 *= dv;
        a0 += __shfl_xor(a0, 8); a0 += __shfl_xor(a0, 16); a0 += __shfl_xor(a0, 32);
        a1 += __shfl_xor(a1, 8); a1 += __shfl_xor(a1, 16); a1 += __shfl_xor(a1, 32);
        a2 += __shfl_xor(a2, 8); a2 += __shfl_xor(a2, 16); a2 += __shfl_xor(a2, 32);
        a3 += __shfl_xor(a3, 8); a3 += __shfl_xor(a3, 16); a3 += __shfl_xor(a3, 32);
        a4 += __shfl_xor(a4, 8); a4 += __shfl_xor(a4, 16); a4 += __shfl_xor(a4, 32);
        a5 += __shfl_xor(a5, 8); a5 += __shfl_xor(a5, 16); a5 += __shfl_xor(a5, 32);
        a6 += __shfl_xor(a6, 8); a6 += __shfl_xor(a6, 16); a6 += __shfl_xor(a6, 32);
        a7 += __shfl_xor(a7, 8); a7 += __shfl_xor(a7, 16); a7 += __shfl_xor(a7, 32);
        if (p8 == 0) {
            float4* dst = (float4*)&tile[m * 68 + (fp3 << 3)];
            dst[0] = make_float4(a0, a1, a2, a3);
            dst[1] = make_float4(a4, a5, a6, a7);
        }
        if (lane == 0) dinvt[m] = dv;
    }
}

__device__ __forceinline__ f32x4 transform_tile(
        const float* tile, const short8* __restrict__ fb,
        const float* __restrict__ wf, int boff, int lane, int wv) {
    short8 Bh0 = fb[(wv << 8) +   0 + lane];
    short8 Bl0 = fb[(wv << 8) +  64 + lane];
    short8 Bh1 = fb[(wv << 8) + 128 + lane];
    short8 Bl1 = fb[(wv << 8) + 192 + lane];
    int mrow = lane & 15, quad = lane >> 4;
    const float* arow = &tile[mrow * 68];
    float4 a0 = *(const float4*)(arow + (quad << 3));
    float4 a1 = *(const float4*)(arow + (quad << 3) + 4);
    float4 a2 = *(const float4*)(arow + 32 + (quad << 3));
    float4 a3 = *(const float4*)(arow + 32 + (quad << 3) + 4);
    float av0[8] = {a0.x, a0.y, a0.z, a0.w, a1.x, a1.y, a1.z, a1.w};
    float av1[8] = {a2.x, a2.y, a2.z, a2.w, a3.x, a3.y, a3.z, a3.w};
    short8 Ah0, Al0, Ah1, Al1;
    #pragma unroll
    for (int j = 0; j < 8; ++j) {
        unsigned short h0 = f2bf(av0[j]);
        Ah0[j] = (short)h0; Al0[j] = (short)f2bf(av0[j] - bf2f(h0));
        unsigned short h1 = f2bf(av1[j]);
        Ah1[j] = (short)h1; Al1[j] = (short)f2bf(av1[j] - bf2f(h1));
    }
    float bias = wf[boff + (wv << 4) + mrow];
    f32x4 c = {bias, bias, bias, bias};
    c = __builtin_amdgcn_mfma_f32_16x16x32_bf16(Ah0, Bh0, c, 0, 0, 0);
    c = __builtin_amdgcn_mfma_f32_16x16x32_bf16(Al0, Bh0, c, 0, 0, 0);
    c = __builtin_amdgcn_mfma_f32_16x16x32_bf16(Ah0, Bl0, c, 0, 0, 0);
    c = __builtin_amdgcn_mfma_f32_16x16x32_bf16(Ah1, Bh1, c, 0, 0, 0);
    c = __builtin_amdgcn_mfma_f32_16x16x32_bf16(Al1, Bh1, c, 0, 0, 0);
    c = __builtin_amdgcn_mfma_f32_16x16x32_bf16(Ah1, Bl1, c, 0, 0, 0);
    return c;
}

// ---- heavy layers ----
template<int FUSE>
__global__ __launch_bounds__(256, 4) void k_layer(
        const unsigned short* __restrict__ hin, unsigned short* __restrict__ hout,
        float* __restrict__ s4,
        const unsigned short* __restrict__ desc, const int* __restrict__ rowp,
        const float* __restrict__ dinv, const float* __restrict__ wf,
        const short8* __restrict__ frag, int mat, int boff) {
    __shared__ float tile[16 * 68];
    __shared__ float dinvt[16];
    __shared__ float pd[4][16];
    int lane = threadIdx.x & 63, wv = threadIdx.x >> 6;
    int b = blockIdx.x;
    int g = b & 7, tb = (b >> 3) << 4;
    const uint4* hg128 = (const uint4*)(hin + ((size_t)g * PITCH << 6));

    gather_tile(hg128, desc, rowp, dinv, tb, lane, wv, tile, dinvt);
    __syncthreads();
    f32x4 c = transform_tile(tile, frag + (mat << 10), wf, boff, lane, wv);

    int mrow = lane & 15, quad = lane >> 4;
    if (!FUSE) {
        #pragma unroll
        for (int r = 0; r < 4; ++r) {
            int m = (quad << 2) + r;
            hout[(((size_t)g * PITCH + tb + m) << 6) + (wv << 4) + mrow] = f2bf(dinvt[m] * tanh_fast(c[r]));
        }
    } else {
        float w4v = wf[W4OFF + (wv << 4) + mrow];
        #pragma unroll
        for (int r = 0; r < 4; ++r) {
            float d = tanh_fast(c[r]) * w4v;
            d += __shfl_xor(d, 1); d += __shfl_xor(d, 2);
            d += __shfl_xor(d, 4); d += __shfl_xor(d, 8);
            if (mrow == 0) pd[wv][(quad << 2) + r] = d;
        }
        __syncthreads();
        if (threadIdx.x < 16)
            s4[g * PITCH + tb + threadIdx.x] = dinvt[threadIdx.x] *
                (pd[0][threadIdx.x] + pd[1][threadIdx.x] + pd[2][threadIdx.x] + pd[3][threadIdx.x]);
    }
}

// ---- prop (R12): 16 lanes per node, 4 nodes/wave, grid 1000 ----
__global__ __launch_bounds__(256) void k_prop(
        const float* __restrict__ s4, const unsigned short* __restrict__ desc,
        const int* __restrict__ rowp, const float* __restrict__ dinv,
        const float* __restrict__ wf,
        float* yin, float* yb, float* kA, float* kB, float* kC,
        float c1, float c2, float c3, float c4, int stage,
        const int* __restrict__ modes, void* out, int hidx) {
    int lane = threadIdx.x & 63, wv = threadIdx.x >> 6;
    int b = blockIdx.x;
    int g = b & 7, tb = (b >> 3) << 4;
    const float* sg = s4 + g * PITCH;
    int grp = lane >> 4, j = lane & 15;
    int local = tb + (wv << 2) + grp;
    int s = rowp[local], e = rowp[local + 1];
    float acc = 0.f;
    for (int i = s + j; i < e; i += 16) acc += sg[desc[i]];
    acc += __shfl_xor(acc, 1); acc += __shfl_xor(acc, 2);
    acc += __shfl_xor(acc, 4); acc += __shfl_xor(acc, 8);
    if (j == 0) {
        int idx = g * PITCH + local;
        float dv = dinv[local];
        float k = dv * acc + wf[B4OFF];
        float ynew = yb[idx] + c1 * kA[idx] + c2 * kB[idx] + c3 * kC[idx] + c4 * k;
        if (stage == 0) kA[idx] = k;
        else if (stage == 1) kB[idx] = k;
        else if (stage == 2) kC[idx] = k;
        yin[idx] = dv * ynew;
        if (stage == 3) {
            yb[idx] = ynew;
            int cn = g * NNODE + local;
            if (modes[0]) ((__hip_bfloat16*)out)[cn * HOR + hidx] = __float2bfloat16(ynew);
            else          ((float*)out)[cn * HOR + hidx] = ynew;
        }
    }
}

// ================= host =================

extern "C" void kernel_launch(void* const* d_in, const int* in_sizes, int n_in,
                              void* d_out, int out_size, void* d_ws, size_t ws_size,
                              hipStream_t stream) {
    char* ws = (char*)d_ws;
    unsigned short* desc = (unsigned short*)(ws + OFF_DESC);
    unsigned short* hA   = (unsigned short*)(ws + OFF_HA);
    unsigned short* hB   = (unsigned short*)(ws + OFF_HB);
    float* yin  = (float*)(ws + OFF_YIN);
    float* yb   = (float*)(ws + OFF_YB);
    float* kA   = (float*)(ws + OFF_KA);
    float* kB   = (float*)(ws + OFF_KB);
    float* kC   = (float*)(ws + OFF_KC);
    float* s4   = (float*)(ws + OFF_S4);
    int*   deg  = (int*)(ws + OFF_DEG);
    int*   cur  = (int*)(ws + OFF_CUR);
    int*   rowp = (int*)(ws + OFF_ROWP);
    float* dinv = (float*)(ws + OFF_DINV);
    int*   modes= (int*)(ws + OFF_MODES);
    float* wf   = (float*)(ws + OFF_WF);
    short8* wfrag = (short8*)(ws + OFF_WFRAG);

    const void* x    = d_in[0];
    const void* eidx = d_in[1];
    WPtrs wp;
    for (int i = 0; i < 10; ++i) wp.p[i] = d_in[2 + i];

    k_detect  <<<1, 64, 0, stream>>>(x, eidx, modes);
    k_setup0  <<<192, 256, 0, stream>>>(deg, (unsigned*)desc, (unsigned*)hA, (unsigned*)hB);
    k_count   <<<EPG / 256, 256, 0, stream>>>(eidx, modes, deg);
    k_scan    <<<1, 256, 0, stream>>>(deg, rowp, cur, dinv);
    k_scatter <<<(EPG + NNODE + 255) / 256, 256, 0, stream>>>(eidx, modes, cur, desc);
    k_convert <<<(WFTOT + 255) / 256, 256, 0, stream>>>(wp, wf, modes);
    k_mkfrag  <<<12, 256, 0, stream>>>(wf, wfrag);
    k_finalize<<<NG * PITCH / 256, 256, 0, stream>>>(dinv, x, modes, yin, yb, s4, d_out);

    const float dt = 10.f / 9.f, dt3 = dt / 3.f;
    const float C1[4] = {0.f,  -dt3, dt,  dt * 0.125f};
    const float C2[4] = {0.f,  0.f,  -dt, dt * 0.375f};
    const float C3[4] = {0.f,  0.f,  0.f, dt * 0.375f};
    const float C4[4] = {dt3,  dt,   dt,  dt * 0.125f};

    k_layer0<<<1000, 256, 0, stream>>>(yin, hA, desc, rowp, dinv, wf);  // initial

    for (int step = 0; step < NSTEP; ++step) {
        for (int st = 0; st < 4; ++st) {
            k_layer<0><<<1000, 256, 0, stream>>>(hA, hB, nullptr, desc, rowp, dinv, wf, wfrag, 0, B1OFF);
            k_layer<0><<<1000, 256, 0, stream>>>(hB, hA, nullptr, desc, rowp, dinv, wf, wfrag, 1, B2OFF);
            k_layer<1><<<1000, 256, 0, stream>>>(hA, nullptr, s4, desc, rowp, dinv, wf, wfrag, 2, B3OFF);
            k_prop    <<<1000, 256, 0, stream>>>(s4, desc, rowp, dinv, wf, yin, yb, kA, kB, kC,
                                                 C1[st], C2[st], C3[st], C4[st], st,
                                                 modes, d_out, step + 1);
            if (step < NSTEP - 1 || st < 3)
                k_layer0<<<1000, 256, 0, stream>>>(yin, hA, desc, rowp, dinv, wf);
        }
    }
}

// Round 13
// 1401.103 us; speedup vs baseline: 1.2771x; 1.0002x over previous
//
#include <hip/hip_runtime.h>
#include <hip/hip_bf16.h>

#define NNODE   2000
#define NG      8
#define EPG     64000
#define TSTEPS  24
#define HOR     10
#define NSTEP   (HOR-1)
#define PITCH   2048          // per-graph node pitch; row 2047 is the zero row
#define ECAP    98304         // padded CSR capacity (ushorts)
#define TILES   125           // 2000 / 16

// ---- workspace layout (bytes) ----
#define OFF_DESC    0
#define OFF_HA      196608
#define OFF_HB      2293760
#define OFF_YIN     4390912
#define OFF_YB      4456448
#define OFF_KA      4521984
#define OFF_KB      4587520
#define OFF_KC      4653056
#define OFF_S4      4718592
#define OFF_DEG     4784128
#define OFF_CUR     4792320
#define OFF_ROWP    4800512
#define OFF_DINV    4808960
#define OFF_MODES   4817152
#define OFF_WF      4817408
#define OFF_WFRAG   4868352
// total ~4.92 MB

#define W0OFF 0
#define B0OFF 64
#define W1OFF 128
#define B1OFF 4224
#define W2OFF 4288
#define B2OFF 8384
#define W3OFF 8448
#define B3OFF 12544
#define W4OFF 12608
#define B4OFF 12672
#define WFTOT 12673

typedef __attribute__((ext_vector_type(8))) short short8;
typedef __attribute__((ext_vector_type(4))) float f32x4;
typedef __attribute__((ext_vector_type(2))) float f32x2;

struct WPtrs { const void* p[10]; };

__device__ inline float tanh_fast(float x) {
    float xc = fminf(fmaxf(x, -15.f), 15.f);
    float e  = __expf(2.f * xc);
    return 1.f - 2.f / (e + 1.f);
}
__device__ inline unsigned short f2bf(float f) {
    unsigned u = __float_as_uint(f);
    u += 0x7fff + ((u >> 16) & 1);
    return (unsigned short)(u >> 16);
}
__device__ inline float bf2f(unsigned short h) {
    return __uint_as_float(((unsigned)h) << 16);
}
__device__ inline int ld_idx(const void* p, long i, int imode) {
    return imode ? (int)((const long long*)p)[i] : ((const int*)p)[i];
}

// unpack one dword (2 bf16 feats) into a register-pair float2 -> feeds v_pk_add_f32
__device__ inline f32x2 unpk(unsigned v) {
    f32x2 r;
    r.x = __uint_as_float(v << 16);
    r.y = __uint_as_float(v & 0xffff0000u);
    return r;
}

// ================= setup kernels =================

__global__ void k_detect(const void* x, const void* eidx, int* modes) {
    int lane = threadIdx.x;
    const unsigned* xw = (const unsigned*)x;
    unsigned w = xw[lane];
    int ex = (w >> 7) & 0xFF;
    unsigned long long m = __ballot(ex >= 100 && ex <= 145);
    const unsigned* ew = (const unsigned*)eidx;
    unsigned long long m2 = __ballot(ew[2*lane + 1] != 0);
    if (lane == 0) {
        modes[0] = (__popcll(m) >= 48) ? 1 : 0;
        modes[1] = (__popcll(m2) == 0) ? 1 : 0;
    }
}

// merged: deg init + desc sentinel fill + h pad-row zeroing
__global__ void k_setup0(int* deg, unsigned* desc32, unsigned* hA32, unsigned* hB32) {
    int n = blockIdx.x * 256 + threadIdx.x;
    if (n < PITCH) deg[n] = (n < NNODE) ? 1 : 0;
    if (n < ECAP / 2) desc32[n] = 0x07FF07FFu;     // sentinel -> zero row 2047
    if (n < 2 * NG * 48 * 32) {
        int b = n / (NG * 48 * 32), r = n % (NG * 48 * 32);
        int g = r / (48 * 32), rr = r % (48 * 32);
        int row = NNODE + rr / 32, fp = rr % 32;
        unsigned* pp = b ? hB32 : hA32;
        pp[(g * PITCH + row) * 32 + fp] = 0;
    }
}

__global__ void k_count(const void* eidx, const int* __restrict__ modes, int* deg) {
    int e = blockIdx.x * 256 + threadIdx.x;
    int imode = modes[1];
    int dst = ld_idx(eidx, (long)EPG + e, imode);
    atomicAdd(&deg[dst], 1);
}

__global__ __launch_bounds__(256) void k_scan(const int* __restrict__ deg, int* rowp,
                                              int* cursor, float* dinv) {
    __shared__ int part[256];
    int t = threadIdx.x, base = t * 8;
    int loc[8]; int s = 0;
    #pragma unroll
    for (int k = 0; k < 8; ++k) {
        int d = deg[base + k];
        int p = (d + 15) & ~15;
        loc[k] = p; s += p;
    }
    part[t] = s; __syncthreads();
    for (int off = 1; off < 256; off <<= 1) {
        int v = (t >= off) ? part[t - off] : 0;
        __syncthreads();
        part[t] += v;
        __syncthreads();
    }
    int run = part[t] - s;
    #pragma unroll
    for (int k = 0; k < 8; ++k) {
        rowp[base + k] = run; cursor[base + k] = run;
        int d = deg[base + k];
        dinv[base + k] = (d > 0) ? rsqrtf((float)d) : 0.f;
        run += loc[k];
    }
    if (t == 255) rowp[PITCH] = part[255];
}

__global__ void k_scatter(const void* eidx, const int* __restrict__ modes,
                          int* cursor, unsigned short* desc) {
    int idx = blockIdx.x * 256 + threadIdx.x;
    if (idx >= EPG + NNODE) return;
    int imode = modes[1];
    int s, d;
    if (idx < EPG) { s = ld_idx(eidx, idx, imode); d = ld_idx(eidx, (long)EPG + idx, imode); }
    else           { s = idx - EPG; d = s; }
    int pos = atomicAdd(&cursor[d], 1);
    desc[pos] = (unsigned short)s;
}

__global__ void k_convert(WPtrs wp, float* wf, const int* __restrict__ modes) {
    int idx = blockIdx.x * 256 + threadIdx.x;
    if (idx >= WFTOT) return;
    int fmode = modes[0];
    const int offs[10]  = {W0OFF,B0OFF,W1OFF,B1OFF,W2OFF,B2OFF,W3OFF,B3OFF,W4OFF,B4OFF};
    const int sizes[10] = {64,64,4096,64,4096,64,4096,64,64,1};
    #pragma unroll
    for (int s = 0; s < 10; ++s) {
        if (idx >= offs[s] && idx < offs[s] + sizes[s]) {
            int j = idx - offs[s];
            wf[idx] = fmode ? __bfloat162float(((const __hip_bfloat16*)wp.p[s])[j])
                            : ((const float*)wp.p[s])[j];
        }
    }
}

__global__ void k_mkfrag(const float* __restrict__ wf, short8* frag) {
    int t = blockIdx.x * 256 + threadIdx.x;
    if (t >= 3072) return;
    int lane = t & 63, half = (t >> 6) & 1, kh = (t >> 7) & 1, nb = (t >> 8) & 3, mat = t >> 10;
    const int woffs[3] = {W1OFF, W2OFF, W3OFF};
    const float* W = wf + woffs[mat];
    int n  = nb * 16 + (lane & 15);
    int k0 = kh * 32 + (lane >> 4) * 8;
    short8 v;
    #pragma unroll
    for (int j = 0; j < 8; ++j) {
        float w = W[(k0 + j) * 64 + n];
        unsigned short h = f2bf(w);
        v[j] = half ? (short)f2bf(w - bf2f(h)) : (short)h;
    }
    frag[t] = v;
}

__global__ void k_finalize(const float* __restrict__ dinv, const void* x,
                           const int* __restrict__ modes,
                           float* yin, float* yb, float* s4, void* out) {
    int idx = blockIdx.x * 256 + threadIdx.x;
    if (idx >= NG * PITCH) return;
    int g = idx >> 11, local = idx & (PITCH - 1);
    if (local >= NNODE) { yin[idx] = 0.f; yb[idx] = 0.f; s4[idx] = 0.f; return; }
    int cn = g * NNODE + local;
    float y0 = modes[0] ? __bfloat162float(((const __hip_bfloat16*)x)[cn * TSTEPS + (TSTEPS - 1)])
                        : ((const float*)x)[cn * TSTEPS + (TSTEPS - 1)];
    yin[idx] = dinv[local] * y0;
    yb[idx]  = y0;
    if (modes[0]) ((__hip_bfloat16*)out)[cn * HOR] = __float2bfloat16(y0);
    else          ((float*)out)[cn * HOR] = y0;
}

// ---- layer 0: 16 lanes per node, 4 nodes/wave, tile/block, grid 1000 ----
__global__ __launch_bounds__(256) void k_layer0(
        const float* __restrict__ yin, unsigned short* __restrict__ hout,
        const unsigned short* __restrict__ desc, const int* __restrict__ rowp,
        const float* __restrict__ dinv, const float* __restrict__ wf) {
    int lane = threadIdx.x & 63, wv = threadIdx.x >> 6;
    int b = blockIdx.x;
    int g = b & 7, tb = (b >> 3) << 4;
    const float* yg = yin + g * PITCH;
    int grp = lane >> 4, j = lane & 15;
    int local = tb + (wv << 2) + grp;
    int s = rowp[local], e = rowp[local + 1];
    float acc = 0.f;
    for (int i = s + j; i < e; i += 16) acc += yg[desc[i]];
    acc += __shfl_xor(acc, 1); acc += __shfl_xor(acc, 2);
    acc += __shfl_xor(acc, 4); acc += __shfl_xor(acc, 8);
    float w0 = wf[W0OFF + lane], b0 = wf[B0OFF + lane];
    #pragma unroll
    for (int r = 0; r < 4; ++r) {
        float Z = __shfl(acc, r << 4);
        int ln = tb + (wv << 2) + r;
        float dv = dinv[ln];
        float o = dv * tanh_fast(dv * Z * w0 + b0);
        hout[((size_t)(g * PITCH + ln) << 6) + lane] = f2bf(o);
    }
}

// ---- R13 heavy gather: dwordx4 rows, 32-edge unroll, PACKED f32x2 accumulators.
// Per dword: shl + and + v_pk_add_f32 (3 VALU) instead of shl+and+2 adds (4). ----
__device__ __forceinline__ void acc8(uint4 v, f32x2& a01, f32x2& a23,
                                     f32x2& a45, f32x2& a67) {
    a01 += unpk(v.x);
    a23 += unpk(v.y);
    a45 += unpk(v.z);
    a67 += unpk(v.w);
}

__device__ __forceinline__ void gather_tile(
        const uint4* __restrict__ hg128, const unsigned short* __restrict__ desc,
        const int* __restrict__ rowp, const float* __restrict__ dinv,
        int tb, int lane, int wv, float* tile, float* dinvt) {
    int fp3 = lane & 7, p8 = lane >> 3;
    #pragma unroll
    for (int r = 0; r < 4; ++r) {
        int m = (wv << 2) + r;
        int local = tb + m;
        int s = rowp[local], e = rowp[local + 1];   // multiples of 16
        f32x2 a01 = {0.f, 0.f}, a23 = {0.f, 0.f}, a45 = {0.f, 0.f}, a67 = {0.f, 0.f};
        int i = s;
        for (; i + 32 <= e; i += 32) {
            unsigned e0 = desc[i + p8];
            unsigned e1 = desc[i + 8 + p8];
            unsigned e2 = desc[i + 16 + p8];
            unsigned e3 = desc[i + 24 + p8];
            uint4 v0 = hg128[(e0 << 3) + fp3];
            uint4 v1 = hg128[(e1 << 3) + fp3];
            uint4 v2 = hg128[(e2 << 3) + fp3];
            uint4 v3 = hg128[(e3 << 3) + fp3];
            acc8(v0, a01, a23, a45, a67);
            acc8(v1, a01, a23, a45, a67);
            acc8(v2, a01, a23, a45, a67);
            acc8(v3, a01, a23, a45, a67);
        }
        if (i < e) {
            unsigned e0 = desc[i + p8];
            unsigned e1 = desc[i + 8 + p8];
            uint4 v0 = hg128[(e0 << 3) + fp3];
            uint4 v1 = hg128[(e1 << 3) + fp3];
            acc8(v0, a01, a23, a45, a67);
            acc8(v1, a01, a23, a45, a67);
        }
        float dv = dinv[local];
        f32x2 dv2 = {dv, dv};
        a01 *= dv2; a23 *= dv2; a45 *= dv2; a67 *= dv2;
        float a0 = a01.x, a1 = a01.y, a2 = a23.x, a3 = a23.y;
        float a4 = a45.x, a5 = a45.y, a6 = a67.x, a7 = a67.y;
        a0 += __shfl_xor(a0, 8); a0 += __shfl_xor(a0, 16); a0 += __shfl_xor(a0, 32);
        a1 += __shfl_xor(a1, 8); a1 += __shfl_xor(a1, 16); a1 += __shfl_xor(a1, 32);
        a2 += __shfl_xor(a2, 8); a2 += __shfl_xor(a2, 16); a2 += __shfl_xor(a2, 32);
        a3 += __shfl_xor(a3, 8); a3 += __shfl_xor(a3, 16); a3 += __shfl_xor(a3, 32);
        a4 += __shfl_xor(a4, 8); a4 += __shfl_xor(a4, 16); a4 += __shfl_xor(a4, 32);
        a5 += __shfl_xor(a5, 8); a5 += __shfl_xor(a5, 16); a5 += __shfl_xor(a5, 32);
        a6 += __shfl_xor(a6, 8); a6 += __shfl_xor(a6, 16); a6 += __shfl_xor(a6, 32);
        a7 += __shfl_xor(a7, 8); a7 += __shfl_xor(a7, 16); a7 += __shfl_xor(a7, 32);
        if (p8 == 0) {
            float4* dst = (float4*)&tile[m * 68 + (fp3 << 3)];
            dst[0] = make_float4(a0, a1, a2, a3);
            dst[1] = make_float4(a4, a5, a6, a7);
        }
        if (lane == 0) dinvt[m] = dv;
    }
}

__device__ __forceinline__ f32x4 transform_tile(
        const float* tile, const short8* __restrict__ fb,
        const float* __restrict__ wf, int boff, int lane, int wv) {
    short8 Bh0 = fb[(wv << 8) +   0 + lane];
    short8 Bl0 = fb[(wv << 8) +  64 + lane];
    short8 Bh1 = fb[(wv << 8) + 128 + lane];
    short8 Bl1 = fb[(wv << 8) + 192 + lane];
    int mrow = lane & 15, quad = lane >> 4;
    const float* arow = &tile[mrow * 68];
    float4 a0 = *(const float4*)(arow + (quad << 3));
    float4 a1 = *(const float4*)(arow + (quad << 3) + 4);
    float4 a2 = *(const float4*)(arow + 32 + (quad << 3));
    float4 a3 = *(const float4*)(arow + 32 + (quad << 3) + 4);
    float av0[8] = {a0.x, a0.y, a0.z, a0.w, a1.x, a1.y, a1.z, a1.w};
    float av1[8] = {a2.x, a2.y, a2.z, a2.w, a3.x, a3.y, a3.z, a3.w};
    short8 Ah0, Al0, Ah1, Al1;
    #pragma unroll
    for (int j = 0; j < 8; ++j) {
        unsigned short h0 = f2bf(av0[j]);
        Ah0[j] = (short)h0; Al0[j] = (short)f2bf(av0[j] - bf2f(h0));
        unsigned short h1 = f2bf(av1[j]);
        Ah1[j] = (short)h1; Al1[j] = (short)f2bf(av1[j] - bf2f(h1));
    }
    float bias = wf[boff + (wv << 4) + mrow];
    f32x4 c = {bias, bias, bias, bias};
    c = __builtin_amdgcn_mfma_f32_16x16x32_bf16(Ah0, Bh0, c, 0, 0, 0);
    c = __builtin_amdgcn_mfma_f32_16x16x32_bf16(Al0, Bh0, c, 0, 0, 0);
    c = __builtin_amdgcn_mfma_f32_16x16x32_bf16(Ah0, Bl0, c, 0, 0, 0);
    c = __builtin_amdgcn_mfma_f32_16x16x32_bf16(Ah1, Bh1, c, 0, 0, 0);
    c = __builtin_amdgcn_mfma_f32_16x16x32_bf16(Al1, Bh1, c, 0, 0, 0);
    c = __builtin_amdgcn_mfma_f32_16x16x32_bf16(Ah1, Bl1, c, 0, 0, 0);
    return c;
}

// ---- heavy layers ----
template<int FUSE>
__global__ __launch_bounds__(256, 4) void k_layer(
        const unsigned short* __restrict__ hin, unsigned short* __restrict__ hout,
        float* __restrict__ s4,
        const unsigned short* __restrict__ desc, const int* __restrict__ rowp,
        const float* __restrict__ dinv, const float* __restrict__ wf,
        const short8* __restrict__ frag, int mat, int boff) {
    __shared__ float tile[16 * 68];
    __shared__ float dinvt[16];
    __shared__ float pd[4][16];
    int lane = threadIdx.x & 63, wv = threadIdx.x >> 6;
    int b = blockIdx.x;
    int g = b & 7, tb = (b >> 3) << 4;
    const uint4* hg128 = (const uint4*)(hin + ((size_t)g * PITCH << 6));

    gather_tile(hg128, desc, rowp, dinv, tb, lane, wv, tile, dinvt);
    __syncthreads();
    f32x4 c = transform_tile(tile, frag + (mat << 10), wf, boff, lane, wv);

    int mrow = lane & 15, quad = lane >> 4;
    if (!FUSE) {
        #pragma unroll
        for (int r = 0; r < 4; ++r) {
            int m = (quad << 2) + r;
            hout[(((size_t)g * PITCH + tb + m) << 6) + (wv << 4) + mrow] = f2bf(dinvt[m] * tanh_fast(c[r]));
        }
    } else {
        float w4v = wf[W4OFF + (wv << 4) + mrow];
        #pragma unroll
        for (int r = 0; r < 4; ++r) {
            float d = tanh_fast(c[r]) * w4v;
            d += __shfl_xor(d, 1); d += __shfl_xor(d, 2);
            d += __shfl_xor(d, 4); d += __shfl_xor(d, 8);
            if (mrow == 0) pd[wv][(quad << 2) + r] = d;
        }
        __syncthreads();
        if (threadIdx.x < 16)
            s4[g * PITCH + tb + threadIdx.x] = dinvt[threadIdx.x] *
                (pd[0][threadIdx.x] + pd[1][threadIdx.x] + pd[2][threadIdx.x] + pd[3][threadIdx.x]);
    }
}

// ---- prop: 16 lanes per node, 4 nodes/wave, grid 1000 ----
__global__ __launch_bounds__(256) void k_prop(
        const float* __restrict__ s4, const unsigned short* __restrict__ desc,
        const int* __restrict__ rowp, const float* __restrict__ dinv,
        const float* __restrict__ wf,
        float* yin, float* yb, float* kA, float* kB, float* kC,
        float c1, float c2, float c3, float c4, int stage,
        const int* __restrict__ modes, void* out, int hidx) {
    int lane = threadIdx.x & 63, wv = threadIdx.x >> 6;
    int b = blockIdx.x;
    int g = b & 7, tb = (b >> 3) << 4;
    const float* sg = s4 + g * PITCH;
    int grp = lane >> 4, j = lane & 15;
    int local = tb + (wv << 2) + grp;
    int s = rowp[local], e = rowp[local + 1];
    float acc = 0.f;
    for (int i = s + j; i < e; i += 16) acc += sg[desc[i]];
    acc += __shfl_xor(acc, 1); acc += __shfl_xor(acc, 2);
    acc += __shfl_xor(acc, 4); acc += __shfl_xor(acc, 8);
    if (j == 0) {
        int idx = g * PITCH + local;
        float dv = dinv[local];
        float k = dv * acc + wf[B4OFF];
        float ynew = yb[idx] + c1 * kA[idx] + c2 * kB[idx] + c3 * kC[idx] + c4 * k;
        if (stage == 0) kA[idx] = k;
        else if (stage == 1) kB[idx] = k;
        else if (stage == 2) kC[idx] = k;
        yin[idx] = dv * ynew;
        if (stage == 3) {
            yb[idx] = ynew;
            int cn = g * NNODE + local;
            if (modes[0]) ((__hip_bfloat16*)out)[cn * HOR + hidx] = __float2bfloat16(ynew);
            else          ((float*)out)[cn * HOR + hidx] = ynew;
        }
    }
}

// ================= host =================

extern "C" void kernel_launch(void* const* d_in, const int* in_sizes, int n_in,
                              void* d_out, int out_size, void* d_ws, size_t ws_size,
                              hipStream_t stream) {
    char* ws = (char*)d_ws;
    unsigned short* desc = (unsigned short*)(ws + OFF_DESC);
    unsigned short* hA   = (unsigned short*)(ws + OFF_HA);
    unsigned short* hB   = (unsigned short*)(ws + OFF_HB);
    float* yin  = (float*)(ws + OFF_YIN);
    float* yb   = (float*)(ws + OFF_YB);
    float* kA   = (float*)(ws + OFF_KA);
    float* kB   = (float*)(ws + OFF_KB);
    float* kC   = (float*)(ws + OFF_KC);
    float* s4   = (float*)(ws + OFF_S4);
    int*   deg  = (int*)(ws + OFF_DEG);
    int*   cur  = (int*)(ws + OFF_CUR);
    int*   rowp = (int*)(ws + OFF_ROWP);
    float* dinv = (float*)(ws + OFF_DINV);
    int*   modes= (int*)(ws + OFF_MODES);
    float* wf   = (float*)(ws + OFF_WF);
    short8* wfrag = (short8*)(ws + OFF_WFRAG);

    const void* x    = d_in[0];
    const void* eidx = d_in[1];
    WPtrs wp;
    for (int i = 0; i < 10; ++i) wp.p[i] = d_in[2 + i];

    k_detect  <<<1, 64, 0, stream>>>(x, eidx, modes);
    k_setup0  <<<192, 256, 0, stream>>>(deg, (unsigned*)desc, (unsigned*)hA, (unsigned*)hB);
    k_count   <<<EPG / 256, 256, 0, stream>>>(eidx, modes, deg);
    k_scan    <<<1, 256, 0, stream>>>(deg, rowp, cur, dinv);
    k_scatter <<<(EPG + NNODE + 255) / 256, 256, 0, stream>>>(eidx, modes, cur, desc);
    k_convert <<<(WFTOT + 255) / 256, 256, 0, stream>>>(wp, wf, modes);
    k_mkfrag  <<<12, 256, 0, stream>>>(wf, wfrag);
    k_finalize<<<NG * PITCH / 256, 256, 0, stream>>>(dinv, x, modes, yin, yb, s4, d_out);

    const float dt = 10.f / 9.f, dt3 = dt / 3.f;
    const float C1[4] = {0.f,  -dt3, dt,  dt * 0.125f};
    const float C2[4] = {0.f,  0.f,  -dt, dt * 0.375f};
    const float C3[4] = {0.f,  0.f,  0.f, dt * 0.375f};
    const float C4[4] = {dt3,  dt,   dt,  dt * 0.125f};

    k_layer0<<<1000, 256, 0, stream>>>(yin, hA, desc, rowp, dinv, wf);  // initial

    for (int step = 0; step < NSTEP; ++step) {
        for (int st = 0; st < 4; ++st) {
            k_layer<0><<<1000, 256, 0, stream>>>(hA, hB, nullptr, desc, rowp, dinv, wf, wfrag, 0, B1OFF);
            k_layer<0><<<1000, 256, 0, stream>>>(hB, hA, nullptr, desc, rowp, dinv, wf, wfrag, 1, B2OFF);
            k_layer<1><<<1000, 256, 0, stream>>>(hA, nullptr, s4, desc, rowp, dinv, wf, wfrag, 2, B3OFF);
            k_prop    <<<1000, 256, 0, stream>>>(s4, desc, rowp, dinv, wf, yin, yb, kA, kB, kC,
                                                 C1[st], C2[st], C3[st], C4[st], st,
                                                 modes, d_out, step + 1);
            if (step < NSTEP - 1 || st < 3)
                k_layer0<<<1000, 256, 0, stream>>>(yin, hA, desc, rowp, dinv, wf);
        }
    }
}